// Round 4
// baseline (998.860 us; speedup 1.0000x reference)
//
#include <hip/hip_runtime.h>
#include <hip/hip_bf16.h>

// Problem constants
#define NN 50000
#define EE 800000
#define NFR 513
#define NMEL 128
#define HC 128      // H*C = 4*32

__device__ __forceinline__ float ldf(const float* p, long i) { return p[i]; }
__device__ __forceinline__ float ldf(const __hip_bfloat16* p, long i) { return __bfloat162float(p[i]); }
__device__ __forceinline__ void stf(float* p, long i, float v) { p[i] = v; }
__device__ __forceinline__ void stf(__hip_bfloat16* p, long i, float v) { p[i] = __float2bfloat16(v); }

// ---------------- Tiled fp32 GEMM: C[M,Nn] = A[M,K] @ B[K,Nn] (+bias, +leaky) ----------------
#define BM 64
#define BN 64
#define BK 16

template<int EPI, typename TA, typename TB, typename TC>
__global__ __launch_bounds__(256) void gemm_k(const TA* __restrict__ A, const TB* __restrict__ B,
                                              TC* __restrict__ C, int M, int Nn, int K,
                                              const float* __restrict__ bias)
{
    __shared__ float As[BK][BM + 4];
    __shared__ float Bs[BK][BN + 4];
    const int t = threadIdx.x;
    const int row0 = blockIdx.x * BM;
    const int col0 = blockIdx.y * BN;
    const int tc = t & 15, tr = t >> 4;
    float acc[4][4] = {};

    for (int kb = 0; kb < K; kb += BK) {
        // A tile: 64 rows x 16 k  (transpose into As[k][row])
        #pragma unroll
        for (int i = 0; i < 4; ++i) {
            int idx = i * 256 + t;
            int r = idx >> 4, k = idx & 15;
            int gr = row0 + r, gk = kb + k;
            float v = 0.f;
            if (gr < M && gk < K) v = ldf(A, (long)gr * K + gk);
            As[k][r] = v;
        }
        // B tile: 16 k x 64 cols
        #pragma unroll
        for (int i = 0; i < 4; ++i) {
            int idx = i * 256 + t;
            int c = idx & 63, k = idx >> 6;
            int gk = kb + k, gc = col0 + c;
            float v = 0.f;
            if (gk < K && gc < Nn) v = ldf(B, (long)gk * Nn + gc);
            Bs[k][c] = v;
        }
        __syncthreads();
        #pragma unroll
        for (int kk = 0; kk < BK; ++kk) {
            float4 av = *reinterpret_cast<const float4*>(&As[kk][tr << 2]);
            float4 bv = *reinterpret_cast<const float4*>(&Bs[kk][tc << 2]);
            float a[4] = {av.x, av.y, av.z, av.w};
            float b[4] = {bv.x, bv.y, bv.z, bv.w};
            #pragma unroll
            for (int i = 0; i < 4; ++i)
                #pragma unroll
                for (int j = 0; j < 4; ++j)
                    acc[i][j] += a[i] * b[j];
        }
        __syncthreads();
    }

    #pragma unroll
    for (int i = 0; i < 4; ++i) {
        int gr = row0 + (tr << 2) + i;
        if (gr >= M) continue;
        #pragma unroll
        for (int j = 0; j < 4; ++j) {
            int gc = col0 + (tc << 2) + j;
            if (gc >= Nn) continue;
            float v = acc[i][j];
            if (EPI == 1) {
                v += bias[gc];
                v = v > 0.f ? v : 0.01f * v;
            }
            stf(C, (long)gr * Nn + gc, v);
        }
    }
}

// ---------------- per-node attention coefficients ----------------
__global__ void k_att(const float* __restrict__ h, const float* __restrict__ att_src,
                      const float* __restrict__ att_dst,
                      float* __restrict__ a_s, float* __restrict__ a_d)
{
    int id = blockIdx.x * blockDim.x + threadIdx.x;
    if (id >= NN * 4) return;
    int n = id >> 2, hh = id & 3;
    const float* hr = h + (long)n * HC + hh * 32;
    float s1 = 0.f, s2 = 0.f;
    #pragma unroll
    for (int c = 0; c < 32; ++c) {
        float v = hr[c];
        s1 += v * att_src[hh * 32 + c];
        s2 += v * att_dst[hh * 32 + c];
    }
    a_s[id] = s1;
    a_d[id] = s2;
}

// ---------------- edge pass 1: denom[d,h] += exp(leakyrelu(a_s[s]+a_d[d])) ----------------
__global__ void k_edge_denom(const int* __restrict__ ei, const float* __restrict__ a_s,
                             const float* __restrict__ a_d, float* __restrict__ denom)
{
    int id = blockIdx.x * blockDim.x + threadIdx.x;
    if (id >= (EE + NN) * 4) return;
    int e = id >> 2, hh = id & 3;
    int s, d;
    if (e < EE) { s = ei[e]; d = ei[EE + e]; } else { s = d = e - EE; }
    float a = a_s[s * 4 + hh] + a_d[d * 4 + hh];
    a = a > 0.f ? a : 0.2f * a;
    atomicAdd(&denom[d * 4 + hh], __expf(a));
}

// ---------------- edge pass 2: agg[d,:] += alpha * h[s,:] ----------------
__global__ __launch_bounds__(256) void k_edge_scatter(const int* __restrict__ ei, const float* __restrict__ a_s,
                                                      const float* __restrict__ a_d, const float* __restrict__ denom,
                                                      const float* __restrict__ hfeat, float* __restrict__ agg)
{
    int eg = blockIdx.x * 2 + (threadIdx.x >> 7);
    int t = threadIdx.x & 127;
    if (eg >= EE + NN) return;
    int s, d;
    if (eg < EE) { s = ei[eg]; d = ei[EE + eg]; } else { s = d = eg - EE; }
    int hh = t >> 5;
    float a = a_s[s * 4 + hh] + a_d[d * 4 + hh];
    a = a > 0.f ? a : 0.2f * a;
    float alpha = __expf(a) / denom[d * 4 + hh];
    atomicAdd(&agg[(long)d * HC + t], alpha * hfeat[(long)s * HC + t]);
}

// ---------------- elu(agg + bias_g) in place ----------------
__global__ void k_act(float* __restrict__ agg, const float* __restrict__ bias_g)
{
    int id = blockIdx.x * blockDim.x + threadIdx.x;
    if (id >= NN * HC) return;
    float v = agg[id] + bias_g[id & (HC - 1)];
    agg[id] = v > 0.f ? v : expm1f(v);
}

// ---------------- final: leaky(x2@W3+b3) -> softmax -> fp32 out ----------------
__global__ __launch_bounds__(256) void k_final(const float* __restrict__ x2, const float* __restrict__ W3,
                                               const float* __restrict__ b3, float* __restrict__ out)
{
    __shared__ float w3s[128 * 10];
    __shared__ float b3s[10];
    int t = threadIdx.x;
    for (int i = t; i < 128 * 10; i += 256) w3s[i] = W3[i];
    if (t < 10) b3s[t] = b3[t];
    __syncthreads();
    int n = blockIdx.x * 256 + t;
    if (n >= NN) return;

    float l[10];
    #pragma unroll
    for (int j = 0; j < 10; ++j) l[j] = b3s[j];
    const float4* row = reinterpret_cast<const float4*>(x2 + (long)n * 128);
    #pragma unroll 4
    for (int k4 = 0; k4 < 32; ++k4) {
        float4 v = row[k4];
        const float vv[4] = {v.x, v.y, v.z, v.w};
        #pragma unroll
        for (int u = 0; u < 4; ++u) {
            float vk = vv[u];
            const float* wrow = &w3s[(k4 * 4 + u) * 10];
            #pragma unroll
            for (int j = 0; j < 10; ++j) l[j] += vk * wrow[j];
        }
    }
    float m = -1e30f;
    #pragma unroll
    for (int j = 0; j < 10; ++j) {
        float v = l[j];
        v = v > 0.f ? v : 0.01f * v;
        l[j] = v;
        m = fmaxf(m, v);
    }
    float sum = 0.f;
    #pragma unroll
    for (int j = 0; j < 10; ++j) { l[j] = __expf(l[j] - m); sum += l[j]; }
    float inv = 1.f / sum;
    #pragma unroll
    for (int j = 0; j < 10; ++j) out[(long)n * 10 + j] = l[j] * inv;
}

extern "C" void kernel_launch(void* const* d_in, const int* in_sizes, int n_in,
                              void* d_out, int out_size, void* d_ws, size_t ws_size,
                              hipStream_t stream)
{
    // Inputs fp32 (reference declares float32); OUTPUT fp32 (softmax of fp32);
    // harness compares at bf16 granularity ("absmax error (bf16, ...)").
    const float* x       = (const float*)d_in[0];
    const int*   ei      = (const int*)d_in[1];
    const float* fb      = (const float*)d_in[2];
    const float* Wg      = (const float*)d_in[3];
    const float* bias_g  = (const float*)d_in[4];
    const float* att_src = (const float*)d_in[5];
    const float* att_dst = (const float*)d_in[6];
    const float* W1      = (const float*)d_in[7];
    const float* b1      = (const float*)d_in[8];
    const float* W2      = (const float*)d_in[9];
    const float* b2      = (const float*)d_in[10];
    const float* W3      = (const float*)d_in[11];
    const float* b3      = (const float*)d_in[12];
    float* out = (float*)d_out;
    float* ws = (float*)d_ws;

    // workspace layout (float units) — peak 13,465,664 floats = 53.9 MB
    //   fbWg  [513,128]    @ 0          (65,664)
    //   a_s   [N,4]        @ 65,664     (200,000)
    //   a_d   [N,4]        @ 265,664    (200,000)
    //   denom [N,4]        @ 465,664    (200,000)
    //   agg   [N,128] f32  @ 665,664    (6,400,000)   -> later aliased by x2 (f32)
    //   hbuf  [N,128] f32  @ 7,065,664  (6,400,000)   -> later aliased by x1 (bf16 [N,256])
    if (ws_size < (size_t)13465664 * sizeof(float)) return;  // diagnostic: leaves out zeroed
    float* fbWg  = ws + 0;
    float* a_s   = ws + 65664;
    float* a_d   = ws + 265664;
    float* denom = ws + 465664;
    float* agg   = ws + 665664;
    float* hbuf  = ws + 7065664;
    __hip_bfloat16* x1b = (__hip_bfloat16*)hbuf;   // [N,256] bf16 (hbuf dead after scatter)
    float* x2    = agg;                            // [N,128] f32 (agg dead after x1-GEMM)

    // zero denom + agg (contiguous range)
    hipMemsetAsync(ws + 465664, 0, (size_t)6600000 * sizeof(float), stream);

    // fbWg = fb @ Wg   [513,128] = [513,128]@[128,128]
    gemm_k<0><<<dim3(9, 2), 256, 0, stream>>>(fb, Wg, fbWg, NFR, HC, NMEL, (const float*)nullptr);

    // h = x @ fbWg     [N,128] = [N,513]@[513,128]
    gemm_k<0><<<dim3((NN + BM - 1) / BM, 2), 256, 0, stream>>>(x, fbWg, hbuf, NN, HC, NFR, (const float*)nullptr);

    // per-node attention coefficients
    k_att<<<(NN * 4 + 255) / 256, 256, 0, stream>>>(hbuf, att_src, att_dst, a_s, a_d);

    // edge softmax denominator
    k_edge_denom<<<((EE + NN) * 4 + 255) / 256, 256, 0, stream>>>(ei, a_s, a_d, denom);

    // weighted scatter-add of messages
    k_edge_scatter<<<(EE + NN + 1) / 2, 256, 0, stream>>>(ei, a_s, a_d, denom, hbuf, agg);

    // elu(agg + bias_g)
    k_act<<<(NN * HC + 255) / 256, 256, 0, stream>>>(agg, bias_g);

    // x1 = leaky(agg @ W1 + b1)   [N,256] bf16 (written over dead hbuf)
    gemm_k<1><<<dim3((NN + BM - 1) / BM, 4), 256, 0, stream>>>(agg, W1, x1b, NN, 256, 128, b1);

    // x2 = leaky(x1 @ W2 + b2)    [N,128] f32 (written over dead agg)
    gemm_k<1><<<dim3((NN + BM - 1) / BM, 2), 256, 0, stream>>>(x1b, W2, x2, NN, 128, 256, b2);

    // out = softmax(leaky(x2 @ W3 + b3))
    k_final<<<(NN + 255) / 256, 256, 0, stream>>>(x2, W3, b3, out);
}

// Round 5
// 780.046 us; speedup vs baseline: 1.2805x; 1.2805x over previous
//
#include <hip/hip_runtime.h>
#include <hip/hip_bf16.h>

// Problem constants
#define NN 50000
#define EE 800000
#define NFR 513
#define NMEL 128
#define HC 128      // H*C = 4*32

__device__ __forceinline__ float ldf(const float* p, long i) { return p[i]; }
__device__ __forceinline__ float ldf(const __hip_bfloat16* p, long i) { return __bfloat162float(p[i]); }
__device__ __forceinline__ void stf(float* p, long i, float v) { p[i] = v; }
__device__ __forceinline__ void stf(__hip_bfloat16* p, long i, float v) { p[i] = __float2bfloat16(v); }

// ---------------- Tiled fp32 GEMM: C[M,Nn] = A[M,K] @ B[K,Nn] (+bias, +leaky) ----------------
#define BM 64
#define BN 64
#define BK 16

template<int EPI, typename TA, typename TB, typename TC>
__global__ __launch_bounds__(256) void gemm_k(const TA* __restrict__ A, const TB* __restrict__ B,
                                              TC* __restrict__ C, int M, int Nn, int K,
                                              const float* __restrict__ bias)
{
    __shared__ float As[BK][BM + 4];
    __shared__ float Bs[BK][BN + 4];
    const int t = threadIdx.x;
    const int row0 = blockIdx.x * BM;
    const int col0 = blockIdx.y * BN;
    const int tc = t & 15, tr = t >> 4;
    float acc[4][4] = {};

    for (int kb = 0; kb < K; kb += BK) {
        #pragma unroll
        for (int i = 0; i < 4; ++i) {
            int idx = i * 256 + t;
            int r = idx >> 4, k = idx & 15;
            int gr = row0 + r, gk = kb + k;
            float v = 0.f;
            if (gr < M && gk < K) v = ldf(A, (long)gr * K + gk);
            As[k][r] = v;
        }
        #pragma unroll
        for (int i = 0; i < 4; ++i) {
            int idx = i * 256 + t;
            int c = idx & 63, k = idx >> 6;
            int gk = kb + k, gc = col0 + c;
            float v = 0.f;
            if (gk < K && gc < Nn) v = ldf(B, (long)gk * Nn + gc);
            Bs[k][c] = v;
        }
        __syncthreads();
        #pragma unroll
        for (int kk = 0; kk < BK; ++kk) {
            float4 av = *reinterpret_cast<const float4*>(&As[kk][tr << 2]);
            float4 bv = *reinterpret_cast<const float4*>(&Bs[kk][tc << 2]);
            float a[4] = {av.x, av.y, av.z, av.w};
            float b[4] = {bv.x, bv.y, bv.z, bv.w};
            #pragma unroll
            for (int i = 0; i < 4; ++i)
                #pragma unroll
                for (int j = 0; j < 4; ++j)
                    acc[i][j] += a[i] * b[j];
        }
        __syncthreads();
    }

    #pragma unroll
    for (int i = 0; i < 4; ++i) {
        int gr = row0 + (tr << 2) + i;
        if (gr >= M) continue;
        #pragma unroll
        for (int j = 0; j < 4; ++j) {
            int gc = col0 + (tc << 2) + j;
            if (gc >= Nn) continue;
            float v = acc[i][j];
            if (EPI == 1) {
                v += bias[gc];
                v = v > 0.f ? v : 0.01f * v;
            }
            stf(C, (long)gr * Nn + gc, v);
        }
    }
}

// ---------------- per-node attention coefficients ----------------
__global__ void k_att(const float* __restrict__ h, const float* __restrict__ att_src,
                      const float* __restrict__ att_dst,
                      float* __restrict__ a_s, float* __restrict__ a_d)
{
    int id = blockIdx.x * blockDim.x + threadIdx.x;
    if (id >= NN * 4) return;
    int n = id >> 2, hh = id & 3;
    const float* hr = h + (long)n * HC + hh * 32;
    float s1 = 0.f, s2 = 0.f;
    #pragma unroll
    for (int c = 0; c < 32; ++c) {
        float v = hr[c];
        s1 += v * att_src[hh * 32 + c];
        s2 += v * att_dst[hh * 32 + c];
    }
    a_s[id] = s1;
    a_d[id] = s2;
}

// ---------------- CSR build: histogram -> scan -> fill ----------------
__global__ void k_hist(const int* __restrict__ ei, int* __restrict__ hist)
{
    int e = blockIdx.x * 256 + threadIdx.x;
    if (e < EE) atomicAdd(&hist[ei[EE + e]], 1);
}

__global__ __launch_bounds__(512) void k_scan1(const int* __restrict__ hist, int* __restrict__ start,
                                               int* __restrict__ aux)
{
    __shared__ int sm[512];
    int t = threadIdx.x, i = blockIdx.x * 512 + t;
    int v = (i < NN) ? hist[i] : 0;
    sm[t] = v;
    __syncthreads();
    for (int off = 1; off < 512; off <<= 1) {
        int x = (t >= off) ? sm[t - off] : 0;
        __syncthreads();
        sm[t] += x;
        __syncthreads();
    }
    if (i < NN) start[i] = sm[t] - v;   // exclusive
    if (t == 511) aux[blockIdx.x] = sm[511];
}

__global__ void k_scan2(int* __restrict__ aux, int nb)
{
    if (blockIdx.x == 0 && threadIdx.x == 0) {
        int run = 0;
        for (int b = 0; b < nb; ++b) { int v = aux[b]; aux[b] = run; run += v; }
    }
}

__global__ __launch_bounds__(512) void k_scan3(int* __restrict__ start, int* __restrict__ cursor,
                                               const int* __restrict__ aux)
{
    int i = blockIdx.x * 512 + threadIdx.x;
    if (i < NN) {
        int v = start[i] + aux[blockIdx.x];
        start[i] = v;
        cursor[i] = v;
    }
    if (i == 0) start[NN] = EE;
}

__global__ void k_fill(const int* __restrict__ ei, int* __restrict__ cursor, int* __restrict__ sorted)
{
    int e = blockIdx.x * 256 + threadIdx.x;
    if (e >= EE) return;
    int s = ei[e], d = ei[EE + e];
    int pos = atomicAdd(&cursor[d], 1);
    sorted[pos] = s;
}

// ---------------- per-node gather-aggregate: softmax + message sum + bias + ELU ----------------
// one 64-lane wave per destination node; each lane owns features 2*lane, 2*lane+1
__global__ __launch_bounds__(256) void k_agg(const int* __restrict__ start, const int* __restrict__ sorted,
                                             const float* __restrict__ a_s, const float* __restrict__ a_d,
                                             const float* __restrict__ h, const float* __restrict__ bias_g,
                                             float* __restrict__ agg)
{
    int wave = threadIdx.x >> 6;
    int lane = threadIdx.x & 63;
    int d = blockIdx.x * 4 + wave;
    if (d >= NN) return;
    int hh = lane >> 4;                 // head of features 2*lane, 2*lane+1
    float ad = a_d[d * 4 + hh];
    int e0 = start[d], e1 = start[d + 1];

    // self-loop contribution
    float a = a_s[d * 4 + hh] + ad;
    a = a > 0.f ? a : 0.2f * a;
    float ex = __expf(a);
    float2 hv = *reinterpret_cast<const float2*>(h + (long)d * HC + 2 * lane);
    float acc0 = ex * hv.x, acc1 = ex * hv.y, dsum = ex;

    for (int e = e0; e < e1; ++e) {
        int s = sorted[e];              // wave-uniform -> broadcast load
        float ae = a_s[s * 4 + hh] + ad;
        ae = ae > 0.f ? ae : 0.2f * ae;
        float exe = __expf(ae);
        float2 hs = *reinterpret_cast<const float2*>(h + (long)s * HC + 2 * lane);
        acc0 += exe * hs.x;
        acc1 += exe * hs.y;
        dsum += exe;
    }

    float inv = 1.f / dsum;
    float2 bg = *reinterpret_cast<const float2*>(bias_g + 2 * lane);
    float v0 = acc0 * inv + bg.x;
    float v1 = acc1 * inv + bg.y;
    v0 = v0 > 0.f ? v0 : expm1f(v0);
    v1 = v1 > 0.f ? v1 : expm1f(v1);
    *reinterpret_cast<float2*>(agg + (long)d * HC + 2 * lane) = make_float2(v0, v1);
}

// ---------------- final: leaky(x2@W3+b3) -> softmax -> fp32 out ----------------
__global__ __launch_bounds__(256) void k_final(const float* __restrict__ x2, const float* __restrict__ W3,
                                               const float* __restrict__ b3, float* __restrict__ out)
{
    __shared__ float w3s[128 * 10];
    __shared__ float b3s[10];
    int t = threadIdx.x;
    for (int i = t; i < 128 * 10; i += 256) w3s[i] = W3[i];
    if (t < 10) b3s[t] = b3[t];
    __syncthreads();
    int n = blockIdx.x * 256 + t;
    if (n >= NN) return;

    float l[10];
    #pragma unroll
    for (int j = 0; j < 10; ++j) l[j] = b3s[j];
    const float4* row = reinterpret_cast<const float4*>(x2 + (long)n * 128);
    #pragma unroll 4
    for (int k4 = 0; k4 < 32; ++k4) {
        float4 v = row[k4];
        const float vv[4] = {v.x, v.y, v.z, v.w};
        #pragma unroll
        for (int u = 0; u < 4; ++u) {
            float vk = vv[u];
            const float* wrow = &w3s[(k4 * 4 + u) * 10];
            #pragma unroll
            for (int j = 0; j < 10; ++j) l[j] += vk * wrow[j];
        }
    }
    float m = -1e30f;
    #pragma unroll
    for (int j = 0; j < 10; ++j) {
        float v = l[j];
        v = v > 0.f ? v : 0.01f * v;
        l[j] = v;
        m = fmaxf(m, v);
    }
    float sum = 0.f;
    #pragma unroll
    for (int j = 0; j < 10; ++j) { l[j] = __expf(l[j] - m); sum += l[j]; }
    float inv = 1.f / sum;
    #pragma unroll
    for (int j = 0; j < 10; ++j) out[(long)n * 10 + j] = l[j] * inv;
}

extern "C" void kernel_launch(void* const* d_in, const int* in_sizes, int n_in,
                              void* d_out, int out_size, void* d_ws, size_t ws_size,
                              hipStream_t stream)
{
    const float* x       = (const float*)d_in[0];
    const int*   ei      = (const int*)d_in[1];
    const float* fb      = (const float*)d_in[2];
    const float* Wg      = (const float*)d_in[3];
    const float* bias_g  = (const float*)d_in[4];
    const float* att_src = (const float*)d_in[5];
    const float* att_dst = (const float*)d_in[6];
    const float* W1      = (const float*)d_in[7];
    const float* b1      = (const float*)d_in[8];
    const float* W2      = (const float*)d_in[9];
    const float* b2      = (const float*)d_in[10];
    const float* W3      = (const float*)d_in[11];
    const float* b3      = (const float*)d_in[12];
    float* out = (float*)d_out;
    float* ws = (float*)d_ws;

    // workspace layout (float-unit offsets) — peak 14,215,800 floats = 56.9 MB
    float* fbWg   = ws + 0;                       //    65,664  [513,128]
    float* a_s    = ws + 65664;                   //   200,000  [N,4]
    float* a_d    = ws + 265664;                  //   200,000  [N,4]
    int*   hist   = (int*)(ws + 465664);          //    50,000
    int*   startA = (int*)(ws + 515664);          //    50,004
    int*   cursor = (int*)(ws + 565668);          //    50,000
    int*   aux    = (int*)(ws + 615668);          //       132
    int*   sorted = (int*)(ws + 615800);          //   800,000
    float* agg    = ws + 1415800;                 // 6,400,000  [N,128]
    float* hbuf   = ws + 7815800;                 // 6,400,000  [N,128]
    __hip_bfloat16* x1b = (__hip_bfloat16*)hbuf;  // [N,256] bf16 (hbuf dead after k_agg)
    float* x2     = agg;                          // [N,128] f32 (agg dead after x1-GEMM)
    if (ws_size < (size_t)14215800 * sizeof(float)) return;  // diagnostic: leaves out zeroed

    // zero the in-degree histogram only
    hipMemsetAsync(hist, 0, 50000 * sizeof(int), stream);

    // fbWg = fb @ Wg   [513,128]
    gemm_k<0><<<dim3(9, 2), 256, 0, stream>>>(fb, Wg, fbWg, NFR, HC, NMEL, (const float*)nullptr);

    // h = x @ fbWg     [N,128] = [N,513]@[513,128]
    gemm_k<0><<<dim3((NN + BM - 1) / BM, 2), 256, 0, stream>>>(x, fbWg, hbuf, NN, HC, NFR, (const float*)nullptr);

    // per-node attention coefficients
    k_att<<<(NN * 4 + 255) / 256, 256, 0, stream>>>(hbuf, att_src, att_dst, a_s, a_d);

    // CSR build: histogram -> 3-kernel exclusive scan -> fill
    const int NB = (NN + 511) / 512;   // 98
    k_hist<<<(EE + 255) / 256, 256, 0, stream>>>(ei, hist);
    k_scan1<<<NB, 512, 0, stream>>>(hist, startA, aux);
    k_scan2<<<1, 64, 0, stream>>>(aux, NB);
    k_scan3<<<NB, 512, 0, stream>>>(startA, cursor, aux);
    k_fill<<<(EE + 255) / 256, 256, 0, stream>>>(ei, cursor, sorted);

    // gather-aggregate (replaces edge_denom + edge_scatter + act)
    k_agg<<<(NN + 3) / 4, 256, 0, stream>>>(startA, sorted, a_s, a_d, hbuf, bias_g, agg);

    // x1 = leaky(agg @ W1 + b1)   [N,256] bf16 (over dead hbuf)
    gemm_k<1><<<dim3((NN + BM - 1) / BM, 4), 256, 0, stream>>>(agg, W1, x1b, NN, 256, 128, b1);

    // x2 = leaky(x1 @ W2 + b2)    [N,128] f32 (over dead agg)
    gemm_k<1><<<dim3((NN + BM - 1) / BM, 2), 256, 0, stream>>>(x1b, W2, x2, NN, 128, 256, b2);

    // out = softmax(leaky(x2 @ W3 + b3))
    k_final<<<(NN + 255) / 256, 256, 0, stream>>>(x2, W3, b3, out);
}

// Round 6
// 496.386 us; speedup vs baseline: 2.0123x; 1.5715x over previous
//
#include <hip/hip_runtime.h>
#include <hip/hip_bf16.h>

// Problem constants
#define NN 50000
#define EE 800000
#define NFR 513
#define NMEL 128
#define HC 128      // H*C = 4*32

typedef __bf16 bf16x8 __attribute__((ext_vector_type(8)));
typedef float floatx4 __attribute__((ext_vector_type(4)));

__device__ __forceinline__ unsigned short f2b(float f) {   // RNE fp32->bf16 bits
    unsigned u = __float_as_uint(f);
    u = (u + 0x7FFFu + ((u >> 16) & 1u)) >> 16;
    return (unsigned short)u;
}
__device__ __forceinline__ float b2f(unsigned short s) {
    return __uint_as_float(((unsigned)s) << 16);
}

__device__ __forceinline__ float ldf(const float* p, long i) { return p[i]; }
__device__ __forceinline__ void stf(float* p, long i, float v) { p[i] = v; }
__device__ __forceinline__ void stf(__hip_bfloat16* p, long i, float v) {
    ((unsigned short*)p)[i] = f2b(v);
}

// ---------------- fp32 vector GEMM (only for tiny fb@Wg). EPI=2: store bf16 transposed, stride 544 ----------------
#define BM 64
#define BN 64
#define BK 16

template<int EPI, typename TA, typename TB, typename TC>
__global__ __launch_bounds__(256) void gemm_k(const TA* __restrict__ A, const TB* __restrict__ B,
                                              TC* __restrict__ C, int M, int Nn, int K,
                                              const float* __restrict__ bias)
{
    __shared__ float As[BK][BM + 4];
    __shared__ float Bs[BK][BN + 4];
    const int t = threadIdx.x;
    const int row0 = blockIdx.x * BM;
    const int col0 = blockIdx.y * BN;
    const int tc = t & 15, tr = t >> 4;
    float acc[4][4] = {};

    for (int kb = 0; kb < K; kb += BK) {
        #pragma unroll
        for (int i = 0; i < 4; ++i) {
            int idx = i * 256 + t;
            int r = idx >> 4, k = idx & 15;
            int gr = row0 + r, gk = kb + k;
            float v = 0.f;
            if (gr < M && gk < K) v = ldf(A, (long)gr * K + gk);
            As[k][r] = v;
        }
        #pragma unroll
        for (int i = 0; i < 4; ++i) {
            int idx = i * 256 + t;
            int c = idx & 63, k = idx >> 6;
            int gk = kb + k, gc = col0 + c;
            float v = 0.f;
            if (gk < K && gc < Nn) v = ldf(B, (long)gk * Nn + gc);
            Bs[k][c] = v;
        }
        __syncthreads();
        #pragma unroll
        for (int kk = 0; kk < BK; ++kk) {
            float4 av = *reinterpret_cast<const float4*>(&As[kk][tr << 2]);
            float4 bv = *reinterpret_cast<const float4*>(&Bs[kk][tc << 2]);
            float a[4] = {av.x, av.y, av.z, av.w};
            float b[4] = {bv.x, bv.y, bv.z, bv.w};
            #pragma unroll
            for (int i = 0; i < 4; ++i)
                #pragma unroll
                for (int j = 0; j < 4; ++j)
                    acc[i][j] += a[i] * b[j];
        }
        __syncthreads();
    }

    #pragma unroll
    for (int i = 0; i < 4; ++i) {
        int gr = row0 + (tr << 2) + i;
        if (gr >= M) continue;
        #pragma unroll
        for (int j = 0; j < 4; ++j) {
            int gc = col0 + (tc << 2) + j;
            if (gc >= Nn) continue;
            float v = acc[i][j];
            if (EPI == 2) {
                stf(C, (long)gc * 544 + gr, v);      // transposed bf16, zero-padded stride
            } else {
                if (EPI == 1) { v += bias[gc]; v = v > 0.f ? v : 0.01f * v; }
                stf(C, (long)gr * Nn + gc, v);
            }
        }
    }
}

// ---------------- transpose-convert: out[n*KP+k] = bf16(in[k*N+n]) ----------------
__global__ void k_trans(const float* __restrict__ in, __hip_bfloat16* __restrict__ outp,
                        int K, int N, int KP)
{
    int id = blockIdx.x * 256 + threadIdx.x;
    if (id >= N * KP) return;
    int n = id / KP, k = id % KP;
    float v = (k < K) ? in[(long)k * N + n] : 0.f;
    ((unsigned short*)outp)[id] = f2b(v);
}

// ---------------- MFMA bf16 GEMM: C[M,Nn] = A[M,K] @ Bt[Nn,KB]^T ----------------
// A: fp32 (row stride K, converted in staging) or bf16 (row stride K, 16B-aligned rows).
// Bt: bf16 [Nn][KB], KB = K zero-padded to multiple of 32.
// 256 threads = 4 waves; tile 128x128; wave = 64x64 via 4x4 MFMAs of 16x16x32.
#define PS 40   // LDS row stride in bf16 units (80 B) -> 2-way bank conflicts only (free)

__device__ __forceinline__ void stageA_t(const float* A, unsigned short* As, int t,
                                         int row0, int M, int K, int kb)
{
    #pragma unroll
    for (int g = 0; g < 4; ++g) {
        int q = g * 256 + t;            // 0..1023 quads
        int row = q >> 3, k4 = (q & 7) * 4;
        int gr = row0 + row, gk = kb + k4;
        ushort4 pk = make_ushort4(0, 0, 0, 0);
        if (gr < M) {
            const float* ap = A + (long)gr * K + gk;
            if (gk + 3 < K) {
                pk.x = f2b(ap[0]); pk.y = f2b(ap[1]); pk.z = f2b(ap[2]); pk.w = f2b(ap[3]);
            } else {
                if (gk + 0 < K) pk.x = f2b(ap[0]);
                if (gk + 1 < K) pk.y = f2b(ap[1]);
                if (gk + 2 < K) pk.z = f2b(ap[2]);
                if (gk + 3 < K) pk.w = f2b(ap[3]);
            }
        }
        *reinterpret_cast<ushort4*>(&As[row * PS + k4]) = pk;
    }
}

__device__ __forceinline__ void stageA_t(const __hip_bfloat16* A, unsigned short* As, int t,
                                         int row0, int M, int K, int kb)
{
    #pragma unroll
    for (int g = 0; g < 2; ++g) {
        int c = g * 256 + t;            // 0..511 16B-chunks
        int row = c >> 2, k8 = (c & 3) * 8;
        int gr = row0 + row;
        uint4 val = make_uint4(0, 0, 0, 0);
        if (gr < M) val = *reinterpret_cast<const uint4*>(A + (long)gr * K + kb + k8);
        *reinterpret_cast<uint4*>(&As[row * PS + k8]) = val;
    }
}

template<int EPI, typename TA, typename TC>
__global__ __launch_bounds__(256) void mgemm(const TA* __restrict__ A,
                                             const __hip_bfloat16* __restrict__ Bt,
                                             TC* __restrict__ C,
                                             int M, int Nn, int K, int KB,
                                             const float* __restrict__ bias)
{
    __shared__ unsigned short As[128 * PS];
    __shared__ unsigned short Bs[128 * PS];
    const int t = threadIdx.x;
    const int row0 = blockIdx.x * 128;
    const int col0 = blockIdx.y * 128;
    const int wave = t >> 6, lane = t & 63;
    const int wm = (wave >> 1) * 64, wn = (wave & 1) * 64;
    const int lm = lane & 15, kq = lane >> 4;

    floatx4 acc[4][4];
    #pragma unroll
    for (int i = 0; i < 4; ++i)
        #pragma unroll
        for (int j = 0; j < 4; ++j)
            acc[i][j] = 0.f;

    for (int kb = 0; kb < KB; kb += 32) {
        // stage A tile (128 x 32 bf16)
        stageA_t(A, As, t, row0, M, K, kb);
        // stage B tile (128 n-rows x 32 k, from pre-transposed bf16 Bt)
        #pragma unroll
        for (int g = 0; g < 2; ++g) {
            int c = g * 256 + t;
            int row = c >> 2, k8 = (c & 3) * 8;
            int gn = col0 + row;
            uint4 val = make_uint4(0, 0, 0, 0);
            if (gn < Nn) val = *reinterpret_cast<const uint4*>(Bt + (long)gn * KB + kb + k8);
            *reinterpret_cast<uint4*>(&Bs[row * PS + k8]) = val;
        }
        __syncthreads();

        bf16x8 af[4], bf[4];
        #pragma unroll
        for (int i = 0; i < 4; ++i)
            af[i] = *reinterpret_cast<const bf16x8*>(&As[(wm + i * 16 + lm) * PS + kq * 8]);
        #pragma unroll
        for (int j = 0; j < 4; ++j)
            bf[j] = *reinterpret_cast<const bf16x8*>(&Bs[(wn + j * 16 + lm) * PS + kq * 8]);
        #pragma unroll
        for (int i = 0; i < 4; ++i)
            #pragma unroll
            for (int j = 0; j < 4; ++j)
                acc[i][j] = __builtin_amdgcn_mfma_f32_16x16x32_bf16(af[i], bf[j], acc[i][j], 0, 0, 0);
        __syncthreads();
    }

    // epilogue: D row=(lane>>4)*4+reg, col=lane&15 within each 16x16 tile
    #pragma unroll
    for (int i = 0; i < 4; ++i) {
        #pragma unroll
        for (int r = 0; r < 4; ++r) {
            int gr = row0 + wm + i * 16 + kq * 4 + r;
            if (gr >= M) continue;
            #pragma unroll
            for (int j = 0; j < 4; ++j) {
                int gc = col0 + wn + j * 16 + lm;
                float v = acc[i][j][r];
                if (EPI == 1) { v += bias[gc]; v = v > 0.f ? v : 0.01f * v; }
                stf(C, (long)gr * Nn + gc, v);
            }
        }
    }
}

// ---------------- per-node attention coefficients (h in bf16) ----------------
__global__ void k_att(const __hip_bfloat16* __restrict__ h, const float* __restrict__ att_src,
                      const float* __restrict__ att_dst,
                      float* __restrict__ a_s, float* __restrict__ a_d)
{
    int id = blockIdx.x * blockDim.x + threadIdx.x;
    if (id >= NN * 4) return;
    int n = id >> 2, hh = id & 3;
    const unsigned short* hr = (const unsigned short*)(h + (long)n * HC + hh * 32);
    float s1 = 0.f, s2 = 0.f;
    #pragma unroll
    for (int c = 0; c < 32; ++c) {
        float v = b2f(hr[c]);
        s1 += v * att_src[hh * 32 + c];
        s2 += v * att_dst[hh * 32 + c];
    }
    a_s[id] = s1;
    a_d[id] = s2;
}

// ---------------- CSR build: histogram -> scan -> fill ----------------
__global__ void k_hist(const int* __restrict__ ei, int* __restrict__ hist)
{
    int e = blockIdx.x * 256 + threadIdx.x;
    if (e < EE) atomicAdd(&hist[ei[EE + e]], 1);
}

__global__ __launch_bounds__(512) void k_scan1(const int* __restrict__ hist, int* __restrict__ start,
                                               int* __restrict__ aux)
{
    __shared__ int sm[512];
    int t = threadIdx.x, i = blockIdx.x * 512 + t;
    int v = (i < NN) ? hist[i] : 0;
    sm[t] = v;
    __syncthreads();
    for (int off = 1; off < 512; off <<= 1) {
        int x = (t >= off) ? sm[t - off] : 0;
        __syncthreads();
        sm[t] += x;
        __syncthreads();
    }
    if (i < NN) start[i] = sm[t] - v;   // exclusive
    if (t == 511) aux[blockIdx.x] = sm[511];
}

__global__ void k_scan2(int* __restrict__ aux, int nb)
{
    if (blockIdx.x == 0 && threadIdx.x == 0) {
        int run = 0;
        for (int b = 0; b < nb; ++b) { int v = aux[b]; aux[b] = run; run += v; }
    }
}

__global__ __launch_bounds__(512) void k_scan3(int* __restrict__ start, int* __restrict__ cursor,
                                               const int* __restrict__ aux)
{
    int i = blockIdx.x * 512 + threadIdx.x;
    if (i < NN) {
        int v = start[i] + aux[blockIdx.x];
        start[i] = v;
        cursor[i] = v;
    }
    if (i == 0) start[NN] = EE;
}

__global__ void k_fill(const int* __restrict__ ei, int* __restrict__ cursor, int* __restrict__ sorted)
{
    int e = blockIdx.x * 256 + threadIdx.x;
    if (e >= EE) return;
    int s = ei[e], d = ei[EE + e];
    int pos = atomicAdd(&cursor[d], 1);
    sorted[pos] = s;
}

// ---------------- per-node gather-aggregate (h, agg in bf16) ----------------
__global__ __launch_bounds__(256) void k_agg(const int* __restrict__ start, const int* __restrict__ sorted,
                                             const float* __restrict__ a_s, const float* __restrict__ a_d,
                                             const __hip_bfloat16* __restrict__ h,
                                             const float* __restrict__ bias_g,
                                             __hip_bfloat16* __restrict__ agg)
{
    int wave = threadIdx.x >> 6;
    int lane = threadIdx.x & 63;
    int d = blockIdx.x * 4 + wave;
    if (d >= NN) return;
    int hh = lane >> 4;                 // head of features 2*lane, 2*lane+1
    float ad = a_d[d * 4 + hh];
    int e0 = start[d], e1 = start[d + 1];

    // self-loop contribution
    float a = a_s[d * 4 + hh] + ad;
    a = a > 0.f ? a : 0.2f * a;
    float ex = __expf(a);
    unsigned hv = *reinterpret_cast<const unsigned*>(h + (long)d * HC + 2 * lane);
    float acc0 = ex * __uint_as_float(hv << 16);
    float acc1 = ex * __uint_as_float(hv & 0xffff0000u);
    float dsum = ex;

    for (int e = e0; e < e1; ++e) {
        int s = sorted[e];              // wave-uniform -> broadcast load
        float ae = a_s[s * 4 + hh] + ad;
        ae = ae > 0.f ? ae : 0.2f * ae;
        float exe = __expf(ae);
        unsigned hs = *reinterpret_cast<const unsigned*>(h + (long)s * HC + 2 * lane);
        acc0 += exe * __uint_as_float(hs << 16);
        acc1 += exe * __uint_as_float(hs & 0xffff0000u);
        dsum += exe;
    }

    float inv = 1.f / dsum;
    float2 bg = *reinterpret_cast<const float2*>(bias_g + 2 * lane);
    float v0 = acc0 * inv + bg.x;
    float v1 = acc1 * inv + bg.y;
    v0 = v0 > 0.f ? v0 : expm1f(v0);
    v1 = v1 > 0.f ? v1 : expm1f(v1);
    unsigned pk = (unsigned)f2b(v0) | ((unsigned)f2b(v1) << 16);
    *reinterpret_cast<unsigned*>((unsigned short*)agg + (long)d * HC + 2 * lane) = pk;
}

// ---------------- final: leaky(x2@W3+b3) -> softmax -> fp32 out ----------------
__global__ __launch_bounds__(256) void k_final(const float* __restrict__ x2, const float* __restrict__ W3,
                                               const float* __restrict__ b3, float* __restrict__ out)
{
    __shared__ float w3s[128 * 10];
    __shared__ float b3s[10];
    int t = threadIdx.x;
    for (int i = t; i < 128 * 10; i += 256) w3s[i] = W3[i];
    if (t < 10) b3s[t] = b3[t];
    __syncthreads();
    int n = blockIdx.x * 256 + t;
    if (n >= NN) return;

    float l[10];
    #pragma unroll
    for (int j = 0; j < 10; ++j) l[j] = b3s[j];
    const float4* row = reinterpret_cast<const float4*>(x2 + (long)n * 128);
    #pragma unroll 4
    for (int k4 = 0; k4 < 32; ++k4) {
        float4 v = row[k4];
        const float vv[4] = {v.x, v.y, v.z, v.w};
        #pragma unroll
        for (int u = 0; u < 4; ++u) {
            float vk = vv[u];
            const float* wrow = &w3s[(k4 * 4 + u) * 10];
            #pragma unroll
            for (int j = 0; j < 10; ++j) l[j] += vk * wrow[j];
        }
    }
    float m = -1e30f;
    #pragma unroll
    for (int j = 0; j < 10; ++j) {
        float v = l[j];
        v = v > 0.f ? v : 0.01f * v;
        l[j] = v;
        m = fmaxf(m, v);
    }
    float sum = 0.f;
    #pragma unroll
    for (int j = 0; j < 10; ++j) { l[j] = __expf(l[j] - m); sum += l[j]; }
    float inv = 1.f / sum;
    #pragma unroll
    for (int j = 0; j < 10; ++j) out[(long)n * 10 + j] = l[j] * inv;
}

extern "C" void kernel_launch(void* const* d_in, const int* in_sizes, int n_in,
                              void* d_out, int out_size, void* d_ws, size_t ws_size,
                              hipStream_t stream)
{
    const float* x       = (const float*)d_in[0];
    const int*   ei      = (const int*)d_in[1];
    const float* fb      = (const float*)d_in[2];
    const float* Wg      = (const float*)d_in[3];
    const float* bias_g  = (const float*)d_in[4];
    const float* att_src = (const float*)d_in[5];
    const float* att_dst = (const float*)d_in[6];
    const float* W1      = (const float*)d_in[7];
    const float* b1      = (const float*)d_in[8];
    const float* W2      = (const float*)d_in[9];
    const float* b2      = (const float*)d_in[10];
    const float* W3      = (const float*)d_in[11];
    const float* b3      = (const float*)d_in[12];
    float* out = (float*)d_out;
    float* ws = (float*)d_ws;

    // workspace layout (float units) — total 14,167,720 floats = 56.67 MB
    float* a_s = ws + 0;                                        //   200,000 [N,4]
    float* a_d = ws + 200000;                                   //   200,000 [N,4]
    __hip_bfloat16* fbWgT = (__hip_bfloat16*)(ws + 400000);     //   [128][544] bf16 (34,816 f)
    __hip_bfloat16* W1T   = (__hip_bfloat16*)(ws + 434816);     //   [256][128] bf16 (16,384 f)
    __hip_bfloat16* W2T   = (__hip_bfloat16*)(ws + 451200);     //   [128][256] bf16 (16,384 f)
    int* hist   = (int*)(ws + 467584);                          //    50,000 (cursor aliases)
    int* startA = (int*)(ws + 517584);                          //    50,004
    int* aux    = (int*)(ws + 567588);                          //       132
    int* sorted = (int*)(ws + 567720);                          //   800,000
    __hip_bfloat16* hbufB = (__hip_bfloat16*)(ws + 1367720);    //   [N,128] bf16 (3,200,000 f)
    __hip_bfloat16* aggB  = (__hip_bfloat16*)(ws + 4567720);    //   [N,128] bf16 (3,200,000 f)
    __hip_bfloat16* x1B   = (__hip_bfloat16*)(ws + 7767720);    //   [N,256] bf16 (6,400,000 f)
    int* cursor = hist;                                         //   alias (hist dead after scan1)
    float* x2 = ws + 1367720;                                   //   [N,128] f32 over dead hbuf+agg
    if (ws_size < (size_t)14167720 * sizeof(float)) return;     //   diagnostic: leaves out zeroed

    // zero fbWgT (for K-pad zeros) .. hist (contiguous region)
    hipMemsetAsync(ws + 400000, 0, (size_t)117584 * sizeof(float), stream);

    // fbWgT = (fb @ Wg)^T as bf16, zero-padded K 513->544
    gemm_k<2, float, float, __hip_bfloat16><<<dim3(9, 2), 256, 0, stream>>>(fb, Wg, fbWgT, NFR, HC, NMEL, nullptr);
    // W1T, W2T: transpose-convert weights
    k_trans<<<128, 256, 0, stream>>>(W1, W1T, 128, 256, 128);
    k_trans<<<128, 256, 0, stream>>>(W2, W2T, 256, 128, 256);

    // h = x @ fbWg   (MFMA bf16; A fp32 converted in staging)  [N,128]
    mgemm<0, float, __hip_bfloat16><<<dim3(391, 1), 256, 0, stream>>>(x, fbWgT, hbufB, NN, HC, NFR, 544, nullptr);

    // per-node attention coefficients
    k_att<<<(NN * 4 + 255) / 256, 256, 0, stream>>>(hbufB, att_src, att_dst, a_s, a_d);

    // CSR build
    k_hist<<<(EE + 255) / 256, 256, 0, stream>>>(ei, hist);
    k_scan1<<<98, 512, 0, stream>>>(hist, startA, aux);
    k_scan2<<<1, 64, 0, stream>>>(aux, 98);
    k_scan3<<<98, 512, 0, stream>>>(startA, cursor, aux);
    k_fill<<<(EE + 255) / 256, 256, 0, stream>>>(ei, cursor, sorted);

    // gather-aggregate: softmax + messages + bias + ELU -> agg bf16
    k_agg<<<(NN + 3) / 4, 256, 0, stream>>>(startA, sorted, a_s, a_d, hbufB, bias_g, aggB);

    // x1 = leaky(agg @ W1 + b1)   [N,256] bf16
    mgemm<1, __hip_bfloat16, __hip_bfloat16><<<dim3(391, 2), 256, 0, stream>>>(aggB, W1T, x1B, NN, 256, 128, 128, b1);

    // x2 = leaky(x1 @ W2 + b2)    [N,128] f32
    mgemm<1, __hip_bfloat16, float><<<dim3(391, 1), 256, 0, stream>>>(x1B, W2T, x2, NN, 128, 256, 256, b2);

    // out = softmax(leaky(x2 @ W3 + b3))
    k_final<<<(NN + 255) / 256, 256, 0, stream>>>(x2, W3, b3, out);
}

// Round 7
// 456.524 us; speedup vs baseline: 2.1880x; 1.0873x over previous
//
#include <hip/hip_runtime.h>
#include <hip/hip_bf16.h>

// Problem constants
#define NN 50000
#define EE 800000
#define NFR 513
#define NMEL 128
#define HC 128      // H*C = 4*32

typedef __bf16 bf16x8 __attribute__((ext_vector_type(8)));
typedef float floatx4 __attribute__((ext_vector_type(4)));

__device__ __forceinline__ unsigned short f2b(float f) {   // RNE fp32->bf16 bits
    unsigned u = __float_as_uint(f);
    u = (u + 0x7FFFu + ((u >> 16) & 1u)) >> 16;
    return (unsigned short)u;
}
__device__ __forceinline__ float b2f(unsigned short s) {
    return __uint_as_float(((unsigned)s) << 16);
}
__device__ __forceinline__ float lexp(float a) {           // exp(leaky_relu(a, 0.2))
    a = a > 0.f ? a : 0.2f * a;
    return __expf(a);
}

__device__ __forceinline__ float ldf(const float* p, long i) { return p[i]; }
__device__ __forceinline__ void stf(float* p, long i, float v) { p[i] = v; }
__device__ __forceinline__ void stf(__hip_bfloat16* p, long i, float v) {
    ((unsigned short*)p)[i] = f2b(v);
}

// ---------------- fp32 vector GEMM (only for tiny fb@Wg). EPI=2: store bf16 transposed, stride 544 ----------------
#define BM 64
#define BN 64
#define BK 16

template<int EPI, typename TA, typename TB, typename TC>
__global__ __launch_bounds__(256) void gemm_k(const TA* __restrict__ A, const TB* __restrict__ B,
                                              TC* __restrict__ C, int M, int Nn, int K,
                                              const float* __restrict__ bias)
{
    __shared__ float As[BK][BM + 4];
    __shared__ float Bs[BK][BN + 4];
    const int t = threadIdx.x;
    const int row0 = blockIdx.x * BM;
    const int col0 = blockIdx.y * BN;
    const int tc = t & 15, tr = t >> 4;
    float acc[4][4] = {};

    for (int kb = 0; kb < K; kb += BK) {
        #pragma unroll
        for (int i = 0; i < 4; ++i) {
            int idx = i * 256 + t;
            int r = idx >> 4, k = idx & 15;
            int gr = row0 + r, gk = kb + k;
            float v = 0.f;
            if (gr < M && gk < K) v = ldf(A, (long)gr * K + gk);
            As[k][r] = v;
        }
        #pragma unroll
        for (int i = 0; i < 4; ++i) {
            int idx = i * 256 + t;
            int c = idx & 63, k = idx >> 6;
            int gk = kb + k, gc = col0 + c;
            float v = 0.f;
            if (gk < K && gc < Nn) v = ldf(B, (long)gk * Nn + gc);
            Bs[k][c] = v;
        }
        __syncthreads();
        #pragma unroll
        for (int kk = 0; kk < BK; ++kk) {
            float4 av = *reinterpret_cast<const float4*>(&As[kk][tr << 2]);
            float4 bv = *reinterpret_cast<const float4*>(&Bs[kk][tc << 2]);
            float a[4] = {av.x, av.y, av.z, av.w};
            float b[4] = {bv.x, bv.y, bv.z, bv.w};
            #pragma unroll
            for (int i = 0; i < 4; ++i)
                #pragma unroll
                for (int j = 0; j < 4; ++j)
                    acc[i][j] += a[i] * b[j];
        }
        __syncthreads();
    }

    #pragma unroll
    for (int i = 0; i < 4; ++i) {
        int gr = row0 + (tr << 2) + i;
        if (gr >= M) continue;
        #pragma unroll
        for (int j = 0; j < 4; ++j) {
            int gc = col0 + (tc << 2) + j;
            if (gc >= Nn) continue;
            float v = acc[i][j];
            if (EPI == 2) {
                stf(C, (long)gc * 544 + gr, v);      // transposed bf16, zero-padded stride
            } else {
                if (EPI == 1) { v += bias[gc]; v = v > 0.f ? v : 0.01f * v; }
                stf(C, (long)gr * Nn + gc, v);
            }
        }
    }
}

// ---------------- transpose-convert: out[n*KP+k] = bf16(in[k*N+n]) ----------------
__global__ void k_trans(const float* __restrict__ in, __hip_bfloat16* __restrict__ outp,
                        int K, int N, int KP)
{
    int id = blockIdx.x * 256 + threadIdx.x;
    if (id >= N * KP) return;
    int n = id / KP, k = id % KP;
    float v = (k < K) ? in[(long)k * N + n] : 0.f;
    ((unsigned short*)outp)[id] = f2b(v);
}

// ---------------- MFMA bf16 GEMM: C[M,Nn] = A[M,K] @ Bt[Nn,KB]^T ----------------
#define PS 40   // LDS row stride in bf16 units (80 B) -> 2-way bank conflicts only (free)

__device__ __forceinline__ void stageA_t(const float* A, unsigned short* As, int t,
                                         int row0, int M, int K, int kb)
{
    #pragma unroll
    for (int g = 0; g < 4; ++g) {
        int q = g * 256 + t;            // 0..1023 quads
        int row = q >> 3, k4 = (q & 7) * 4;
        int gr = row0 + row, gk = kb + k4;
        ushort4 pk = make_ushort4(0, 0, 0, 0);
        if (gr < M) {
            const float* ap = A + (long)gr * K + gk;
            if (gk + 3 < K) {
                pk.x = f2b(ap[0]); pk.y = f2b(ap[1]); pk.z = f2b(ap[2]); pk.w = f2b(ap[3]);
            } else {
                if (gk + 0 < K) pk.x = f2b(ap[0]);
                if (gk + 1 < K) pk.y = f2b(ap[1]);
                if (gk + 2 < K) pk.z = f2b(ap[2]);
                if (gk + 3 < K) pk.w = f2b(ap[3]);
            }
        }
        *reinterpret_cast<ushort4*>(&As[row * PS + k4]) = pk;
    }
}

__device__ __forceinline__ void stageA_t(const __hip_bfloat16* A, unsigned short* As, int t,
                                         int row0, int M, int K, int kb)
{
    #pragma unroll
    for (int g = 0; g < 2; ++g) {
        int c = g * 256 + t;            // 0..511 16B-chunks
        int row = c >> 2, k8 = (c & 3) * 8;
        int gr = row0 + row;
        uint4 val = make_uint4(0, 0, 0, 0);
        if (gr < M) val = *reinterpret_cast<const uint4*>(A + (long)gr * K + kb + k8);
        *reinterpret_cast<uint4*>(&As[row * PS + k8]) = val;
    }
}

template<int EPI, typename TA, typename TC>
__global__ __launch_bounds__(256) void mgemm(const TA* __restrict__ A,
                                             const __hip_bfloat16* __restrict__ Bt,
                                             TC* __restrict__ C,
                                             int M, int Nn, int K, int KB,
                                             const float* __restrict__ bias)
{
    __shared__ unsigned short As[128 * PS];
    __shared__ unsigned short Bs[128 * PS];
    const int t = threadIdx.x;
    const int row0 = blockIdx.x * 128;
    const int col0 = blockIdx.y * 128;
    const int wave = t >> 6, lane = t & 63;
    const int wm = (wave >> 1) * 64, wn = (wave & 1) * 64;
    const int lm = lane & 15, kq = lane >> 4;

    floatx4 acc[4][4];
    #pragma unroll
    for (int i = 0; i < 4; ++i)
        #pragma unroll
        for (int j = 0; j < 4; ++j)
            acc[i][j] = 0.f;

    for (int kb = 0; kb < KB; kb += 32) {
        stageA_t(A, As, t, row0, M, K, kb);
        #pragma unroll
        for (int g = 0; g < 2; ++g) {
            int c = g * 256 + t;
            int row = c >> 2, k8 = (c & 3) * 8;
            int gn = col0 + row;
            uint4 val = make_uint4(0, 0, 0, 0);
            if (gn < Nn) val = *reinterpret_cast<const uint4*>(Bt + (long)gn * KB + kb + k8);
            *reinterpret_cast<uint4*>(&Bs[row * PS + k8]) = val;
        }
        __syncthreads();

        bf16x8 af[4], bf[4];
        #pragma unroll
        for (int i = 0; i < 4; ++i)
            af[i] = *reinterpret_cast<const bf16x8*>(&As[(wm + i * 16 + lm) * PS + kq * 8]);
        #pragma unroll
        for (int j = 0; j < 4; ++j)
            bf[j] = *reinterpret_cast<const bf16x8*>(&Bs[(wn + j * 16 + lm) * PS + kq * 8]);
        #pragma unroll
        for (int i = 0; i < 4; ++i)
            #pragma unroll
            for (int j = 0; j < 4; ++j)
                acc[i][j] = __builtin_amdgcn_mfma_f32_16x16x32_bf16(af[i], bf[j], acc[i][j], 0, 0, 0);
        __syncthreads();
    }

    #pragma unroll
    for (int i = 0; i < 4; ++i) {
        #pragma unroll
        for (int r = 0; r < 4; ++r) {
            int gr = row0 + wm + i * 16 + kq * 4 + r;
            if (gr >= M) continue;
            #pragma unroll
            for (int j = 0; j < 4; ++j) {
                int gc = col0 + wn + j * 16 + lm;
                float v = acc[i][j][r];
                if (EPI == 1) { v += bias[gc]; v = v > 0.f ? v : 0.01f * v; }
                stf(C, (long)gr * Nn + gc, v);
            }
        }
    }
}

// ---------------- per-node attention coefficients (h in bf16) ----------------
__global__ void k_att(const __hip_bfloat16* __restrict__ h, const float* __restrict__ att_src,
                      const float* __restrict__ att_dst,
                      float* __restrict__ a_s, float* __restrict__ a_d)
{
    int id = blockIdx.x * blockDim.x + threadIdx.x;
    if (id >= NN * 4) return;
    int n = id >> 2, hh = id & 3;
    const unsigned short* hr = (const unsigned short*)(h + (long)n * HC + hh * 32);
    float s1 = 0.f, s2 = 0.f;
    #pragma unroll
    for (int c = 0; c < 32; ++c) {
        float v = b2f(hr[c]);
        s1 += v * att_src[hh * 32 + c];
        s2 += v * att_dst[hh * 32 + c];
    }
    a_s[id] = s1;
    a_d[id] = s2;
}

// ---------------- CSR build: histogram -> scan -> fill ----------------
__global__ void k_hist(const int* __restrict__ ei, int* __restrict__ hist)
{
    int e = blockIdx.x * 256 + threadIdx.x;
    if (e < EE) atomicAdd(&hist[ei[EE + e]], 1);
}

__global__ __launch_bounds__(512) void k_scan1(const int* __restrict__ hist, int* __restrict__ start,
                                               int* __restrict__ aux)
{
    __shared__ int sm[512];
    int t = threadIdx.x, i = blockIdx.x * 512 + t;
    int v = (i < NN) ? hist[i] : 0;
    sm[t] = v;
    __syncthreads();
    for (int off = 1; off < 512; off <<= 1) {
        int x = (t >= off) ? sm[t - off] : 0;
        __syncthreads();
        sm[t] += x;
        __syncthreads();
    }
    if (i < NN) start[i] = sm[t] - v;   // exclusive
    if (t == 511) aux[blockIdx.x] = sm[511];
}

__global__ void k_scan2(int* __restrict__ aux, int nb)
{
    if (blockIdx.x == 0 && threadIdx.x == 0) {
        int run = 0;
        for (int b = 0; b < nb; ++b) { int v = aux[b]; aux[b] = run; run += v; }
    }
}

__global__ __launch_bounds__(512) void k_scan3(int* __restrict__ start, int* __restrict__ cursor,
                                               const int* __restrict__ aux)
{
    int i = blockIdx.x * 512 + threadIdx.x;
    if (i < NN) {
        int v = start[i] + aux[blockIdx.x];
        start[i] = v;
        cursor[i] = v;
    }
    if (i == 0) start[NN] = EE;
}

__global__ void k_fill(const int* __restrict__ ei, int* __restrict__ cursor, int* __restrict__ sorted)
{
    int e = blockIdx.x * 256 + threadIdx.x;
    if (e >= EE) return;
    int s = ei[e], d = ei[EE + e];
    int pos = atomicAdd(&cursor[d], 1);
    sorted[pos] = s;
}

// ---------------- per-node gather-aggregate, unrolled x4 for memory-level parallelism ----------------
__global__ __launch_bounds__(256) void k_agg(const int* __restrict__ start, const int* __restrict__ sorted,
                                             const float* __restrict__ a_s, const float* __restrict__ a_d,
                                             const __hip_bfloat16* __restrict__ h,
                                             const float* __restrict__ bias_g,
                                             __hip_bfloat16* __restrict__ agg)
{
    int wave = threadIdx.x >> 6;
    int lane = threadIdx.x & 63;
    int d = blockIdx.x * 4 + wave;
    if (d >= NN) return;
    int hh = lane >> 4;                 // head of features 2*lane, 2*lane+1
    float ad = a_d[d * 4 + hh];
    int e0 = start[d], e1 = start[d + 1];

    // self-loop contribution
    float ex = lexp(a_s[d * 4 + hh] + ad);
    unsigned hv = *reinterpret_cast<const unsigned*>(h + (long)d * HC + 2 * lane);
    float acc0 = ex * __uint_as_float(hv << 16);
    float acc1 = ex * __uint_as_float(hv & 0xffff0000u);
    float dsum = ex;

    int e = e0;
    for (; e + 4 <= e1; e += 4) {
        // 4 independent index loads, then 4 independent a_s + 4 independent row loads
        int s0 = sorted[e + 0], s1 = sorted[e + 1], s2 = sorted[e + 2], s3 = sorted[e + 3];
        float as0 = a_s[s0 * 4 + hh], as1 = a_s[s1 * 4 + hh];
        float as2 = a_s[s2 * 4 + hh], as3 = a_s[s3 * 4 + hh];
        unsigned h0 = *reinterpret_cast<const unsigned*>(h + (long)s0 * HC + 2 * lane);
        unsigned h1 = *reinterpret_cast<const unsigned*>(h + (long)s1 * HC + 2 * lane);
        unsigned h2 = *reinterpret_cast<const unsigned*>(h + (long)s2 * HC + 2 * lane);
        unsigned h3 = *reinterpret_cast<const unsigned*>(h + (long)s3 * HC + 2 * lane);
        float x0 = lexp(as0 + ad), x1 = lexp(as1 + ad), x2 = lexp(as2 + ad), x3 = lexp(as3 + ad);
        acc0 += x0 * __uint_as_float(h0 << 16);
        acc1 += x0 * __uint_as_float(h0 & 0xffff0000u);
        acc0 += x1 * __uint_as_float(h1 << 16);
        acc1 += x1 * __uint_as_float(h1 & 0xffff0000u);
        acc0 += x2 * __uint_as_float(h2 << 16);
        acc1 += x2 * __uint_as_float(h2 & 0xffff0000u);
        acc0 += x3 * __uint_as_float(h3 << 16);
        acc1 += x3 * __uint_as_float(h3 & 0xffff0000u);
        dsum += x0 + x1 + x2 + x3;
    }
    for (; e < e1; ++e) {
        int s = sorted[e];
        float xe = lexp(a_s[s * 4 + hh] + ad);
        unsigned hs = *reinterpret_cast<const unsigned*>(h + (long)s * HC + 2 * lane);
        acc0 += xe * __uint_as_float(hs << 16);
        acc1 += xe * __uint_as_float(hs & 0xffff0000u);
        dsum += xe;
    }

    float inv = 1.f / dsum;
    float2 bg = *reinterpret_cast<const float2*>(bias_g + 2 * lane);
    float v0 = acc0 * inv + bg.x;
    float v1 = acc1 * inv + bg.y;
    v0 = v0 > 0.f ? v0 : expm1f(v0);
    v1 = v1 > 0.f ? v1 : expm1f(v1);
    unsigned pk = (unsigned)f2b(v0) | ((unsigned)f2b(v1) << 16);
    *reinterpret_cast<unsigned*>((unsigned short*)agg + (long)d * HC + 2 * lane) = pk;
}

// ---------------- final: leaky(x2@W3+b3) -> softmax -> fp32 out (x2 in bf16) ----------------
__global__ __launch_bounds__(256) void k_final(const __hip_bfloat16* __restrict__ x2, const float* __restrict__ W3,
                                               const float* __restrict__ b3, float* __restrict__ out)
{
    __shared__ float w3s[128 * 10];
    __shared__ float b3s[10];
    int t = threadIdx.x;
    for (int i = t; i < 128 * 10; i += 256) w3s[i] = W3[i];
    if (t < 10) b3s[t] = b3[t];
    __syncthreads();
    int n = blockIdx.x * 256 + t;
    if (n >= NN) return;

    float l[10];
    #pragma unroll
    for (int j = 0; j < 10; ++j) l[j] = b3s[j];
    const uint4* row = reinterpret_cast<const uint4*>(x2 + (long)n * 128);
    #pragma unroll 4
    for (int c8 = 0; c8 < 16; ++c8) {
        uint4 v = row[c8];
        const unsigned w[4] = {v.x, v.y, v.z, v.w};
        #pragma unroll
        for (int u = 0; u < 4; ++u) {
            float f0 = __uint_as_float(w[u] << 16);
            float f1 = __uint_as_float(w[u] & 0xffff0000u);
            const float* wr = &w3s[(c8 * 8 + u * 2) * 10];
            #pragma unroll
            for (int j = 0; j < 10; ++j) l[j] += f0 * wr[j] + f1 * wr[10 + j];
        }
    }
    float m = -1e30f;
    #pragma unroll
    for (int j = 0; j < 10; ++j) {
        float v = l[j];
        v = v > 0.f ? v : 0.01f * v;
        l[j] = v;
        m = fmaxf(m, v);
    }
    float sum = 0.f;
    #pragma unroll
    for (int j = 0; j < 10; ++j) { l[j] = __expf(l[j] - m); sum += l[j]; }
    float inv = 1.f / sum;
    #pragma unroll
    for (int j = 0; j < 10; ++j) out[(long)n * 10 + j] = l[j] * inv;
}

extern "C" void kernel_launch(void* const* d_in, const int* in_sizes, int n_in,
                              void* d_out, int out_size, void* d_ws, size_t ws_size,
                              hipStream_t stream)
{
    const float* x       = (const float*)d_in[0];
    const int*   ei      = (const int*)d_in[1];
    const float* fb      = (const float*)d_in[2];
    const float* Wg      = (const float*)d_in[3];
    const float* bias_g  = (const float*)d_in[4];
    const float* att_src = (const float*)d_in[5];
    const float* att_dst = (const float*)d_in[6];
    const float* W1      = (const float*)d_in[7];
    const float* b1      = (const float*)d_in[8];
    const float* W2      = (const float*)d_in[9];
    const float* b2      = (const float*)d_in[10];
    const float* W3      = (const float*)d_in[11];
    const float* b3      = (const float*)d_in[12];
    float* out = (float*)d_out;
    float* ws = (float*)d_ws;

    // workspace layout (float units) — total 14,167,720 floats = 56.67 MB
    float* a_s = ws + 0;                                        //   200,000 [N,4]
    float* a_d = ws + 200000;                                   //   200,000 [N,4]
    __hip_bfloat16* fbWgT = (__hip_bfloat16*)(ws + 400000);     //   [128][544] bf16 (34,816 f)
    __hip_bfloat16* W1T   = (__hip_bfloat16*)(ws + 434816);     //   [256][128] bf16 (16,384 f)
    __hip_bfloat16* W2T   = (__hip_bfloat16*)(ws + 451200);     //   [128][256] bf16 (16,384 f)
    int* hist   = (int*)(ws + 467584);                          //    50,000 (cursor aliases)
    int* startA = (int*)(ws + 517584);                          //    50,004
    int* aux    = (int*)(ws + 567588);                          //       132
    int* sorted = (int*)(ws + 567720);                          //   800,000
    __hip_bfloat16* hbufB = (__hip_bfloat16*)(ws + 1367720);    //   [N,128] bf16 (3,200,000 f)
    __hip_bfloat16* aggB  = (__hip_bfloat16*)(ws + 4567720);    //   [N,128] bf16 (3,200,000 f)
    __hip_bfloat16* x1B   = (__hip_bfloat16*)(ws + 7767720);    //   [N,256] bf16 (6,400,000 f)
    int* cursor = hist;                                         //   alias (hist dead after scan1)
    __hip_bfloat16* x2B = hbufB;                                //   [N,128] bf16 over dead hbuf
    if (ws_size < (size_t)14167720 * sizeof(float)) return;     //   diagnostic: leaves out zeroed

    // zero fbWgT (for K-pad zeros) .. hist (contiguous region)
    hipMemsetAsync(ws + 400000, 0, (size_t)117584 * sizeof(float), stream);

    // fbWgT = (fb @ Wg)^T as bf16, zero-padded K 513->544
    gemm_k<2, float, float, __hip_bfloat16><<<dim3(9, 2), 256, 0, stream>>>(fb, Wg, fbWgT, NFR, HC, NMEL, nullptr);
    // W1T, W2T: transpose-convert weights
    k_trans<<<128, 256, 0, stream>>>(W1, W1T, 128, 256, 128);
    k_trans<<<128, 256, 0, stream>>>(W2, W2T, 256, 128, 256);

    // h = x @ fbWg   (MFMA bf16; A fp32 converted in staging)  [N,128]
    mgemm<0, float, __hip_bfloat16><<<dim3(391, 1), 256, 0, stream>>>(x, fbWgT, hbufB, NN, HC, NFR, 544, nullptr);

    // per-node attention coefficients
    k_att<<<(NN * 4 + 255) / 256, 256, 0, stream>>>(hbufB, att_src, att_dst, a_s, a_d);

    // CSR build
    k_hist<<<(EE + 255) / 256, 256, 0, stream>>>(ei, hist);
    k_scan1<<<98, 512, 0, stream>>>(hist, startA, aux);
    k_scan2<<<1, 64, 0, stream>>>(aux, 98);
    k_scan3<<<98, 512, 0, stream>>>(startA, cursor, aux);
    k_fill<<<(EE + 255) / 256, 256, 0, stream>>>(ei, cursor, sorted);

    // gather-aggregate: softmax + messages + bias + ELU -> agg bf16
    k_agg<<<(NN + 3) / 4, 256, 0, stream>>>(startA, sorted, a_s, a_d, hbufB, bias_g, aggB);

    // x1 = leaky(agg @ W1 + b1)   [N,256] bf16
    mgemm<1, __hip_bfloat16, __hip_bfloat16><<<dim3(391, 2), 256, 0, stream>>>(aggB, W1T, x1B, NN, 256, 128, 128, b1);

    // x2 = leaky(x1 @ W2 + b2)    [N,128] bf16 (over dead hbuf)
    mgemm<1, __hip_bfloat16, __hip_bfloat16><<<dim3(391, 1), 256, 0, stream>>>(x1B, W2T, x2B, NN, 128, 256, 256, b2);

    // out = softmax(leaky(x2 @ W3 + b3))
    k_final<<<(NN + 255) / 256, 256, 0, stream>>>(x2B, W3, b3, out);
}